// Round 6
// baseline (125.044 us; speedup 1.0000x reference)
//
#include <hip/hip_runtime.h>

// 100x100 sliding mean over x[32][1][1124][1124] f32 -> out[32][1][1025][1025] f32.
// Two passes. H: horizontal 100-sum -> T (f16, stride 1032) in d_ws.
//             V: vertical 100-sum + 1e-4 scale.
// Cache plan: x reads are nontemporal (read-once, keep out of L3); T (74 MB)
// and out (134 MB) are cached (sum 208 MB < 256 MB Infinity Cache), so pass V
// reads T from L3 and its HBM cost is just the output write-back.

#define H_IN    1124
#define W_IN    1124
#define KWIN    100
#define W_OUT   1025
#define H_OUT   1025
#define TSTR    1032   // T row stride in halves (2064 B -> 16B-aligned rows)
#define NBANDS  24
#define BANDR   43     // 24*43 = 1032 >= 1025

typedef float    f32x4 __attribute__((ext_vector_type(4)));
typedef _Float16 f16x8 __attribute__((ext_vector_type(8)));

struct alignas(8) h4 { _Float16 a, b, c, d; };

// ---------------- Pass H: one block per input row, f16 T output -------------
__global__ __launch_bounds__(256) void hslide_kernel(
    const float* __restrict__ x,     // [g*1124][1124]
    _Float16* __restrict__ T)        // [g*1124][TSTR]
{
    __shared__ float srow[W_IN];     // 1124 floats
    __shared__ float ps[282];        // ps[j] = srow[4j] + .. + srow[4j+3]

    const int row = blockIdx.x;
    const int tid = threadIdx.x;
    const f32x4* xr4 = (const f32x4*)(x + (size_t)row * W_IN);

    for (int i = tid; i < 281; i += 256)
        ((f32x4*)srow)[i] = __builtin_nontemporal_load(xr4 + i);
    __syncthreads();

    float4 lo = ((const float4*)srow)[tid];
    ps[tid] = lo.x + lo.y + lo.z + lo.w;
    if (tid < 25) {
        float4 v = ((const float4*)srow)[256 + tid];
        ps[256 + tid] = v.x + v.y + v.z + v.w;
    }
    __syncthreads();

    _Float16* trow = T + (size_t)row * TSTR;
    {
        const int w0 = tid * 4;
        float s = 0.f;
        #pragma unroll
        for (int j = 0; j < 25; ++j) s += ps[tid + j];   // taps w0..w0+99
        float4 hi = ((const float4*)srow)[tid + 25];     // srow[w0+100..w0+103]
        float s1 = s  + hi.x - lo.x;
        float s2 = s1 + hi.y - lo.y;
        float s3 = s2 + hi.z - lo.z;
        *(h4*)(trow + w0) = h4{ (_Float16)s, (_Float16)s1,
                                (_Float16)s2, (_Float16)s3 };   // 8B store, cached
        if (tid == 255) {
            float t = 0.f;
            #pragma unroll
            for (int j = 0; j < 25; ++j) t += ps[256 + j];      // taps 1024..1123
            *(h4*)(trow + 1024) = h4{ (_Float16)t, (_Float16)0.f,
                                      (_Float16)0.f, (_Float16)0.f };
            *(h4*)(trow + 1028) = h4{ (_Float16)0.f, (_Float16)0.f,
                                      (_Float16)0.f, (_Float16)0.f };
        }
    }
}

// ---------------- Pass V: 8 f16 cols/thread, 128-thread blocks --------------
// grid (1, NBANDS, g). Thread 127 additionally owns column 1024.
__global__ __launch_bounds__(128) void vslide_kernel(
    const _Float16* __restrict__ T,  // [g*1124][TSTR]
    float* __restrict__ out)         // [g][1025][1025]
{
    const int tid  = threadIdx.x;
    const int band = blockIdx.y;
    const int b    = blockIdx.z;
    const int r0   = band * BANDR;
    const int nr   = min(BANDR, H_OUT - r0);

    const int w0 = tid * 8;
    const _Float16* base  = T + ((size_t)b * H_IN + r0) * TSTR + w0;   // 16B-aligned
    const _Float16* basec = T + ((size_t)b * H_IN + r0) * TSTR + 1024;
    const bool xtra = (tid == 127);
    const float scale = 1.0f / (float)(KWIN * KWIN);

    float s[8];
    #pragma unroll
    for (int j = 0; j < 8; ++j) s[j] = 0.f;
    float s8 = 0.f;

    // prologue: sum rows r0 .. r0+99
    {
        const _Float16* p  = base;
        const _Float16* pc = basec;
        #pragma unroll 5
        for (int c = 0; c < 25; ++c) {
            f16x8 v0 = *(const f16x8*)(p);
            f16x8 v1 = *(const f16x8*)(p + TSTR);
            f16x8 v2 = *(const f16x8*)(p + 2 * TSTR);
            f16x8 v3 = *(const f16x8*)(p + 3 * TSTR);
            #pragma unroll
            for (int j = 0; j < 8; ++j)
                s[j] += ((float)v0[j] + (float)v1[j])
                      + ((float)v2[j] + (float)v3[j]);
            if (xtra)
                s8 += ((float)pc[0] + (float)pc[TSTR])
                    + ((float)pc[2 * TSTR] + (float)pc[3 * TSTR]);
            p += 4 * TSTR; pc += 4 * TSTR;
        }
    }

    float* q = out + ((size_t)b * H_OUT + r0) * W_OUT + w0;

    #pragma unroll
    for (int j = 0; j < 8; ++j) q[j] = s[j] * scale;
    if (xtra) q[8] = s8 * scale;          // col 1024
    q += W_OUT;

    // steady: add row r0+100+i, sub row r0+i, emit row r0+1+i
    const _Float16* padd  = base  + (size_t)KWIN * TSTR;
    const _Float16* psub  = base;
    const _Float16* paddc = basec + (size_t)KWIN * TSTR;
    const _Float16* psubc = basec;
    const int steps = nr - 1;
    #pragma unroll 4
    for (int i = 0; i < steps; ++i) {
        f16x8 a = *(const f16x8*)padd;  padd += TSTR;
        f16x8 d = *(const f16x8*)psub;  psub += TSTR;
        #pragma unroll
        for (int j = 0; j < 8; ++j)
            s[j] += (float)a[j] - (float)d[j];
        #pragma unroll
        for (int j = 0; j < 8; ++j) q[j] = s[j] * scale;
        if (xtra) {
            s8 += (float)paddc[0] - (float)psubc[0];
            paddc += TSTR; psubc += TSTR;
            q[8] = s8 * scale;
        }
        q += W_OUT;
    }
}

extern "C" void kernel_launch(void* const* d_in, const int* in_sizes, int n_in,
                              void* d_out, int out_size, void* d_ws, size_t ws_size,
                              hipStream_t stream) {
    const float* x = (const float*)d_in[0];
    float* out     = (float*)d_out;
    _Float16* ws   = (_Float16*)d_ws;

    const int B = 32;
    const size_t perBatchT = (size_t)H_IN * TSTR * sizeof(_Float16);  // ~2.32 MB

    int G = (int)(ws_size / perBatchT);
    if (G > B) G = B;
    if (G < 1) G = 1;

    for (int b0 = 0; b0 < B; b0 += G) {
        const int g = (B - b0 < G) ? (B - b0) : G;

        hslide_kernel<<<g * H_IN, 256, 0, stream>>>(
            x + (size_t)b0 * H_IN * W_IN, ws);

        dim3 vgrid(1, NBANDS, g);
        vslide_kernel<<<vgrid, 128, 0, stream>>>(
            ws, out + (size_t)b0 * H_OUT * W_OUT);
    }
}